// Round 4
// baseline (18960.701 us; speedup 1.0000x reference)
//
#include <hip/hip_runtime.h>
#include <hip/hip_bf16.h>

// Bidirectional 2-layer LSTM, T=1024 B=64 H=512. Inputs/outputs fp32, compute
// bf16 MFMA. Persistent kernel: 256 WGs = 4 stages (L0F,L0B,L1F,L1B) x 64 WGs;
// each WG owns 8 h-cols (32 gate cols x K=1024 bf16 = 64 KB LDS, XOR-swizzled).
// L1 elastically chases L0 via W=16 ring.
//
// R5: flags + wave-parallel poll (no atomic RMW contention).
// R6: fence-free coherence (agent-scope write-through stores / cache-bypass
//     loads for ring data; no buffer_wbl2/inv in the loop).
// R7: epoch aggregation + waits overlapped with x-part GEMM.
// R8 (this): the ring GEMM phases were serializing ONE FABRIC LATENCY PER
// UNROLL ITERATION: atomic loads are ordered memrefs, the scheduler refuses
// to hoist them across the interleaved MFMAs/ds_reads, so each kk waited
// ~700cy -> ~5us per phase, 3 phases ~= the whole 18us round. Changes:
//  - ring_gemm<>: source-level software pipeline. Double-buffered register
//    groups (4 kk x 2 bufs = 16 loads in flight); consumption waits at
//    vmcnt(8) with the next group already issued. Exposed ~= fill latency.
//  - h publication coalesced through LDS: gates write f32 h to a 2KB LDS
//    tile; wave 0 re-reads rows and emits 2 coherent 8B stores per row
//    (2 wave-instructions/WG vs 512 scattered 2B fabric write-throughs),
//    plus coalesced float4 out stores for L1.

typedef __hip_bfloat16 bf16;
typedef short bf16x8 __attribute__((ext_vector_type(8)));   // 8 bf16 = 4 VGPRs
typedef float f32x4 __attribute__((ext_vector_type(4)));
typedef unsigned long long u64;

constexpr int T = 1024, B = 64, H = 512, G4 = 2048;
constexpr int W = 16;         // ring slots per direction
constexpr int NW = 64;        // WGs per stage
constexpr int FSTRIDE = 16;   // unsigneds between flag slots (64 B)
constexpr int ESTRIDE = 16;   // unsigneds between epoch slots (64 B)
constexpr size_t OUT_ELEMS = (size_t)T * B * 1024;          // 67,108,864
constexpr size_t HID_OFF   = OUT_ELEMS;                     // hidden [4,64,512]
constexpr size_t CELL_OFF  = OUT_ELEMS + (size_t)4 * B * H; // cell   [4,64,512]

__device__ __align__(256) unsigned g_flags[4 * NW * FSTRIDE]; // per-WG flags
__device__ __align__(256) unsigned g_epoch[4 * ESTRIDE];      // per-stage epoch
__device__ __align__(256) bf16 g_ring [2 * W * B * H];  // L0 h rings (F,B) 2MB
__device__ __align__(256) bf16 g_ring2[2 * W * B * H];  // L1 h rings (F,B) 2MB

__global__ void init_ctrs() {
  const int i = blockIdx.x * blockDim.x + threadIdx.x;
  if (i < 4 * NW * FSTRIDE) g_flags[i] = 0;
  if (i < 4 * ESTRIDE)      g_epoch[i] = 0;
}

__device__ __forceinline__ bf16x8 cvt8(const float* p) {
  const float4 u = *(const float4*)p;
  const float4 v = *(const float4*)(p + 4);
  union { bf16 h[8]; bf16x8 r; } o;
  o.h[0] = __float2bfloat16(u.x); o.h[1] = __float2bfloat16(u.y);
  o.h[2] = __float2bfloat16(u.z); o.h[3] = __float2bfloat16(u.w);
  o.h[4] = __float2bfloat16(v.x); o.h[5] = __float2bfloat16(v.y);
  o.h[6] = __float2bfloat16(v.z); o.h[7] = __float2bfloat16(v.w);
  return o.r;
}

// 16B ring read as two 8B device-coherent (agent-scope) loads: bypasses the
// (possibly stale) local L1/L2, sources from the coherence point.
__device__ __forceinline__ bf16x8 ld16_dev(const bf16* p) {
  union { u64 u[2]; bf16x8 v; } r;
  r.u[0] = __hip_atomic_load((const u64*)p,     __ATOMIC_RELAXED,
                             __HIP_MEMORY_SCOPE_AGENT);
  r.u[1] = __hip_atomic_load((const u64*)p + 1, __ATOMIC_RELAXED,
                             __HIP_MEMORY_SCOPE_AGENT);
  return r.v;
}

// Wave-parallel (64 lanes): lane l watches slot l until ALL slots >= tgt.
__device__ __forceinline__ void wave_poll(const unsigned* base, int lane,
                                          unsigned tgt) {
  const unsigned* p = base + lane * FSTRIDE;
  for (;;) {
    unsigned v = __hip_atomic_load(p, __ATOMIC_RELAXED,
                                   __HIP_MEMORY_SCOPE_AGENT);
    if (__all((int)(v >= tgt))) break;
    __builtin_amdgcn_s_sleep(1);
  }
}

// Single-lane poll of one word.
__device__ __forceinline__ void poll_ge(const unsigned* p, unsigned tgt) {
  while (__hip_atomic_load(p, __ATOMIC_RELAXED,
                           __HIP_MEMORY_SCOPE_AGENT) < tgt)
    __builtin_amdgcn_s_sleep(1);
}

// Software-pipelined ring-slice GEMM half: K=512 as 16 kk steps, A rows
// {arow, arow+16} from device-coherent ring memory, B from LDS (swizzled).
// Double-buffered groups of 4 kk -> 16 loads in flight; consumption of group
// g waits vmcnt(8) while group g+1 flies and g+2 issues behind it.
template<int WBASE>
__device__ __forceinline__ void ring_gemm(const bf16* abase,      // + arow*H
                                          const bf16* Wl, int nb, int sw,
                                          int quad, f32x4& acc0, f32x4& acc1) {
  bf16x8 P0[4], P1[4], Q0[4], Q1[4];
  #pragma unroll
  for (int u = 0; u < 4; ++u) {              // issue group 0 (kk 0..3)
    const int blk = u * 4 + quad;
    P0[u] = ld16_dev(abase + blk * 8);
    P1[u] = ld16_dev(abase + (size_t)16 * H + blk * 8);
  }
  #pragma unroll
  for (int u = 0; u < 4; ++u) {              // issue group 1 (kk 4..7)
    const int blk = (4 + u) * 4 + quad;
    Q0[u] = ld16_dev(abase + blk * 8);
    Q1[u] = ld16_dev(abase + (size_t)16 * H + blk * 8);
  }
  #pragma unroll
  for (int g = 0; g < 4; ++g) {
    #pragma unroll
    for (int u = 0; u < 4; ++u) {            // consume group g
      const int kk   = g * 4 + u;
      const int wblk = WBASE + kk * 4 + quad;
      bf16x8 bfr = *(const bf16x8*)(Wl + nb * 1024 + ((wblk ^ sw) * 8));
      bf16x8 a0 = (g & 1) ? Q0[u] : P0[u];
      bf16x8 a1 = (g & 1) ? Q1[u] : P1[u];
      acc0 = __builtin_amdgcn_mfma_f32_16x16x32_bf16(a0, bfr, acc0, 0, 0, 0);
      acc1 = __builtin_amdgcn_mfma_f32_16x16x32_bf16(a1, bfr, acc1, 0, 0, 0);
    }
    if (g < 2) {                             // refill freed buffer (g+2)
      #pragma unroll
      for (int u = 0; u < 4; ++u) {
        const int kk2 = (g + 2) * 4 + u;
        const int blk = kk2 * 4 + quad;
        if (g & 1) {
          Q0[u] = ld16_dev(abase + blk * 8);
          Q1[u] = ld16_dev(abase + (size_t)16 * H + blk * 8);
        } else {
          P0[u] = ld16_dev(abase + blk * 8);
          P1[u] = ld16_dev(abase + (size_t)16 * H + blk * 8);
        }
      }
    }
  }
}

__global__ void __launch_bounds__(256, 1)
lstm_bidir(const float* __restrict__ x,
           const float* Wxf, const float* bxf, const float* Whf, const float* bhf,
           const float* Wxb, const float* bxb, const float* Whb, const float* bhb,
           float* out)
{
  __shared__ bf16 Wl[32 * 1024];   // 64 KB: 32 gate-col rows x K=1024 (swizzled)
  __shared__ float sh[64][8];      // 2 KB: per-round h tile (f32), for coalesce

  const int tid   = threadIdx.x;
  const int bid   = blockIdx.x;
  const int stage = bid & 3;       // L0F,L0B,L1F,L1B
  const int wg    = bid >> 2;      // 0..63
  const int dir   = stage & 1;
  const int layer = stage >> 1;
  const int c0    = wg * 8;        // h-col base owned by this WG

  const float* Wx = dir ? Wxb : Wxf;
  const float* Wh = dir ? Whb : Whf;
  const float* bx = dir ? bxb : bxf;
  const float* bh = dir ? bhb : bhf;
  bf16* ring  = g_ring  + (size_t)dir * W * B * H;  // L0 h (also L1's x source)
  bf16* ring2 = g_ring2 + (size_t)dir * W * B * H;  // L1 h recurrence

  // ---- stage weight slice into LDS (fp32 -> bf16); row n = j*4+g
  // 16B block kb stored at physical block kb ^ (n&7)  (bank de-conflict)
  for (int c = tid; c < 32 * 128; c += 256) {
    const int n  = c >> 7;               // 0..31
    const int kb = c & 127;              // 16B-bf16 block in K
    const int ke = kb * 8;               // elem offset 0..1016
    const int j = n >> 2, g = n & 3;
    const size_t row = (size_t)layer * G4 + (size_t)g * H + (c0 + j);
    const float* src = (ke < H) ? (Wx + row * H + ke) : (Wh + row * H + (ke - H));
    bf16x8 wv = cvt8(src);
    *(bf16x8*)(Wl + n * 1024 + ((kb ^ (n & 7)) * 8)) = wv;
  }

  const int lane = tid & 63, wi = tid >> 6;   // 4 waves
  const int quad = lane >> 4, mr = lane & 15;
  const int g2 = wi & 1;          // wave's 16-col group
  const int mh = wi >> 1;         // wave's 32-row half
  const int nb = g2 * 16 + mr;    // gate col within WG (0..31)
  const int j  = nb >> 2, gg = nb & 3;        // h-col within WG, gate id
  const int sw = nb & 7;          // swizzle key for this lane's B row

  const size_t brow = (size_t)layer * G4 + (size_t)gg * H + (c0 + j);
  const float bias = bx[brow] + bh[brow];     // fp32

  __syncthreads();  // weights ready (intra-WG)

  float cst[2][4] = {};           // c-state rows mh*32+m*16+quad*4+rr, col j
  unsigned nrounds = 0;           // rounds completed by this WG
  unsigned*       myflags   = g_flags + stage * NW * FSTRIDE;
  unsigned*       myepoch   = g_epoch + stage * ESTRIDE;
  const unsigned* prodepoch = g_epoch + dir * ESTRIDE;        // L1 <- L0
  const unsigned* consepoch = g_epoch + (2 + dir) * ESTRIDE;  // L0 <- L1

  const int r0 = (stage < 2) ? 0 : 1;
  for (int r = r0; r < r0 + T; ++r) {
    int t;
    if (stage == 0)      t = r;
    else if (stage == 1) t = (T - 1) - r;
    else if (stage == 2) t = r - 1;
    else                 t = T - r;

    const bool first = dir ? (t == T - 1) : (t == 0);
    const bool last  = dir ? (t == 0) : (t == T - 1);

    const float* xf = nullptr;      // L0: fp32 x
    const bf16 *xsb = nullptr;      // L1: bf16 x (= L0 ring)
    const bf16 *hsrc; bf16* hdst_bf; float* hdst_f32 = nullptr;
    if (stage < 2) {
      xf      = x    + (size_t)t * B * H;
      hsrc    = ring + (size_t)((r - 1) & (W - 1)) * B * H;
      hdst_bf = ring + (size_t)(r & (W - 1)) * B * H;
    } else {
      xsb      = ring  + (size_t)((r - 1) & (W - 1)) * B * H;  // L0's h for step t
      hsrc     = ring2 + (size_t)((r - 1) & (W - 1)) * B * H;  // own h_{t-1}
      hdst_bf  = ring2 + (size_t)(r & (W - 1)) * B * H;
      hdst_f32 = out + (size_t)t * B * 1024 + (size_t)dir * H;
    }

    // ---- GEMM: C[64,32] = [x_t ; h_{t-1}] (K=1024) @ Wslice, fp32 accum
    f32x4 acc0 = {0.f, 0.f, 0.f, 0.f};
    f32x4 acc1 = {0.f, 0.f, 0.f, 0.f};
    const int arow = mh * 32 + mr;

    if (stage < 2) {
      #pragma unroll
      for (int kk = 0; kk < 16; ++kk) {   // x part (fp32 -> bf16): K 0..511
        const int blk = kk * 4 + quad;
        bf16x8 bfr = *(const bf16x8*)(Wl + nb * 1024 + ((blk ^ sw) * 8));
        const float* ap = xf + (size_t)arow * H + blk * 8;
        bf16x8 a0 = cvt8(ap);
        bf16x8 a1 = cvt8(ap + (size_t)16 * H);
        acc0 = __builtin_amdgcn_mfma_f32_16x16x32_bf16(a0, bfr, acc0, 0, 0, 0);
        acc1 = __builtin_amdgcn_mfma_f32_16x16x32_bf16(a1, bfr, acc1, 0, 0, 0);
      }
      // ---- waits, hidden behind the x-part GEMM above:
      //  siblings done round r-1 (gates h-part reads) + L1 back-pressure
      //  (gates this round's ring writes).
      if (tid < 64) {
        if (wg == 0) {
          wave_poll(myflags, tid, nrounds);       // scan 64 flags (aggregator)
          if (tid == 0) {
            __hip_atomic_store(myepoch, nrounds, __ATOMIC_RELAXED,
                               __HIP_MEMORY_SCOPE_AGENT);
            if (r >= W) poll_ge(consepoch, (unsigned)(r - W + 1));
          }
        } else if (tid == 0) {
          poll_ge(myepoch, nrounds);              // single-word sibling wait
          if (r >= W) poll_ge(consepoch, (unsigned)(r - W + 1));
        }
      }
      __syncthreads();
      if (!first)
        ring_gemm<64>(hsrc + (size_t)arow * H, Wl, nb, sw, quad, acc0, acc1);
    } else {
      // producer wait: every L0 WG published round r. Steady state: L0 runs
      // up to ~W ahead -> this poll is a single satisfied fabric load.
      if (tid == 0) poll_ge(prodepoch, (unsigned)r);
      __syncthreads();
      ring_gemm<0>(xsb + (size_t)arow * H, Wl, nb, sw, quad, acc0, acc1);
      // sibling wait (gates h-part), hidden behind the x-part GEMM above.
      if (tid < 64) {
        if (wg == 0) {
          wave_poll(myflags, tid, nrounds);
          if (tid == 0)
            __hip_atomic_store(myepoch, nrounds, __ATOMIC_RELAXED,
                               __HIP_MEMORY_SCOPE_AGENT);
        } else if (tid == 0) {
          poll_ge(myepoch, nrounds);
        }
      }
      __syncthreads();
      if (!first)
        ring_gemm<64>(hsrc + (size_t)arow * H, Wl, nb, sw, quad, acc0, acc1);
    }

    // ---- gates: lane holds gate gg of (row, col j); partners in lanes ^1^2^3
    #pragma unroll
    for (int m = 0; m < 2; ++m) {
      const f32x4 av = m ? acc1 : acc0;
      #pragma unroll
      for (int rr = 0; rr < 4; ++rr) {
        const float v  = av[rr] + bias;
        const float v1 = __shfl_xor(v, 1);
        const float v2 = __shfl_xor(v, 2);
        const float v3 = __shfl_xor(v, 3);
        float gi, gf, gc, go;
        if (gg == 0)      { gi = v;  gf = v1; gc = v2; go = v3; }
        else if (gg == 1) { gi = v1; gf = v;  gc = v3; go = v2; }
        else if (gg == 2) { gi = v2; gf = v3; gc = v;  go = v1; }
        else              { gi = v3; gf = v2; gc = v1; go = v;  }
        const float si = 1.f / (1.f + __expf(-gi));
        const float sf = 1.f / (1.f + __expf(-gf));
        const float so = 1.f / (1.f + __expf(-go));
        const float tc = 1.f - 2.f / (1.f + __expf(2.f * gc));   // tanh, sat-safe
        const float c2 = sf * cst[m][rr] + si * tc;
        cst[m][rr] = c2;
        const float th = 1.f - 2.f / (1.f + __expf(2.f * c2));
        const float hv = so * th;
        if (gg == 0) {
          const int b = mh * 32 + m * 16 + quad * 4 + rr;
          sh[b][j] = hv;                         // stage for coalesced publish
          if (last) {
            const size_t p = (size_t)(dir * 2 + layer) * (B * H) + (size_t)b * H + (c0 + j);
            out[HID_OFF + p]  = hv;
            out[CELL_OFF + p] = c2;
          }
        }
      }
    }

    // ---- coalesced publish: wave 0 re-reads the 64x8 f32 tile and emits
    // 2 coherent 8B ring stores per row (+ float4 out stores for L1), then
    // drains and the flag goes up. Other waves pass the final barrier and
    // start the next round's x-part immediately.
    __syncthreads();    // sh complete
    if (tid < 64) {
      const int b = tid;
      const float4 u0 = *(const float4*)&sh[b][0];
      const float4 u1 = *(const float4*)&sh[b][4];
      union { bf16 h[8]; u64 q[2]; } o;
      o.h[0] = __float2bfloat16(u0.x); o.h[1] = __float2bfloat16(u0.y);
      o.h[2] = __float2bfloat16(u0.z); o.h[3] = __float2bfloat16(u0.w);
      o.h[4] = __float2bfloat16(u1.x); o.h[5] = __float2bfloat16(u1.y);
      o.h[6] = __float2bfloat16(u1.z); o.h[7] = __float2bfloat16(u1.w);
      bf16* rp = hdst_bf + (size_t)b * H + c0;
      __hip_atomic_store((u64*)rp,     o.q[0], __ATOMIC_RELAXED,
                         __HIP_MEMORY_SCOPE_AGENT);
      __hip_atomic_store((u64*)rp + 1, o.q[1], __ATOMIC_RELAXED,
                         __HIP_MEMORY_SCOPE_AGENT);
      if (stage >= 2) {
        float* op = hdst_f32 + (size_t)b * 1024 + c0;
        *(float4*)op       = u0;
        *(float4*)(op + 4) = u1;
      }
      asm volatile("s_waitcnt vmcnt(0)" ::: "memory");  // ring stores visible
    }
    __syncthreads();    // wave 0 done with sh + stores drained
    ++nrounds;
    if (tid == 0) {
      __hip_atomic_store(myflags + wg * FSTRIDE, nrounds,
                         __ATOMIC_RELAXED, __HIP_MEMORY_SCOPE_AGENT);
    }
  }

  // final epoch publish (consumers' last-round targets reference epoch == T)
  if (wg == 0 && tid < 64) {
    wave_poll(myflags, tid, (unsigned)T);
    if (tid == 0)
      __hip_atomic_store(myepoch, (unsigned)T, __ATOMIC_RELAXED,
                         __HIP_MEMORY_SCOPE_AGENT);
  }
}

extern "C" void kernel_launch(void* const* d_in, const int* in_sizes, int n_in,
                              void* d_out, int out_size, void* d_ws, size_t ws_size,
                              hipStream_t stream) {
  const float* x   = (const float*)d_in[0];
  const float* Wxf = (const float*)d_in[1];
  const float* bxf = (const float*)d_in[2];
  const float* Whf = (const float*)d_in[3];
  const float* bhf = (const float*)d_in[4];
  const float* Wxb = (const float*)d_in[5];
  const float* bxb = (const float*)d_in[6];
  const float* Whb = (const float*)d_in[7];
  const float* bhb = (const float*)d_in[8];
  float* out = (float*)d_out;

  hipLaunchKernelGGL(init_ctrs, dim3(16), dim3(256), 0, stream);
  hipLaunchKernelGGL(lstm_bidir, dim3(256), dim3(256), 0, stream,
                     x, Wxf, bxf, Whf, bhf, Wxb, bxb, Whb, bhb, out);
}

// Round 5
// 15714.276 us; speedup vs baseline: 1.2066x; 1.2066x over previous
//
#include <hip/hip_runtime.h>
#include <hip/hip_bf16.h>

// Bidirectional 2-layer LSTM, T=1024 B=64 H=512. Inputs/outputs fp32, compute
// bf16 MFMA. Persistent kernel: 256 WGs = 4 stages (L0F,L0B,L1F,L1B) x 64 WGs;
// each WG owns 8 h-cols (32 gate cols x K=1024 bf16 = 64 KB LDS, XOR-swizzled).
// L1 elastically chases L0 via W=16 ring.
//
// R5: flags + wave-parallel poll (no atomic RMW contention).
// R6: fence-free coherence (agent-scope write-through stores / cache-bypass
//     loads for ring data; no buffer_wbl2/inv in the loop).
// R7: epoch aggregation + waits overlapped with x-part GEMM.
// R8: source-level SW pipelining of atomic ring loads + coalesced publish.
//     -> FLAT. Conclusion: the compiler serializes __hip_atomic_load chains
//     regardless of source order (ordered memrefs); the ~18us floor since R2
//     is exposed fabric latency per atomic-load pair, not scheduling.
// R9 (this): ring-read phases rewritten as raw inline-asm
//     global_load_dwordx4 ... sc0 sc1 (same coherence semantics, plain VMEM
//     to the compiler), issued in 2 explicit batches of 16 with hand-placed
//     s_waitcnt vmcnt(16)/vmcnt(0) + sched_barrier(0) (T14/rule-18 pattern).
//     All 32 loads of a phase in flight before the first wait -> phase ~=
//     issue + ONE fabric latency (~0.5us) instead of ~7us.

typedef __hip_bfloat16 bf16;
typedef short bf16x8 __attribute__((ext_vector_type(8)));   // 8 bf16 = 4 VGPRs
typedef float f32x4 __attribute__((ext_vector_type(4)));
typedef unsigned long long u64;

constexpr int T = 1024, B = 64, H = 512, G4 = 2048;
constexpr int W = 16;         // ring slots per direction
constexpr int NW = 64;        // WGs per stage
constexpr int FSTRIDE = 16;   // unsigneds between flag slots (64 B)
constexpr int ESTRIDE = 16;   // unsigneds between epoch slots (64 B)
constexpr size_t OUT_ELEMS = (size_t)T * B * 1024;          // 67,108,864
constexpr size_t HID_OFF   = OUT_ELEMS;                     // hidden [4,64,512]
constexpr size_t CELL_OFF  = OUT_ELEMS + (size_t)4 * B * H; // cell   [4,64,512]

__device__ __align__(256) unsigned g_flags[4 * NW * FSTRIDE]; // per-WG flags
__device__ __align__(256) unsigned g_epoch[4 * ESTRIDE];      // per-stage epoch
__device__ __align__(256) bf16 g_ring [2 * W * B * H];  // L0 h rings (F,B) 2MB
__device__ __align__(256) bf16 g_ring2[2 * W * B * H];  // L1 h rings (F,B) 2MB

__global__ void init_ctrs() {
  const int i = blockIdx.x * blockDim.x + threadIdx.x;
  if (i < 4 * NW * FSTRIDE) g_flags[i] = 0;
  if (i < 4 * ESTRIDE)      g_epoch[i] = 0;
}

__device__ __forceinline__ bf16x8 cvt8(const float* p) {
  const float4 u = *(const float4*)p;
  const float4 v = *(const float4*)(p + 4);
  union { bf16 h[8]; bf16x8 r; } o;
  o.h[0] = __float2bfloat16(u.x); o.h[1] = __float2bfloat16(u.y);
  o.h[2] = __float2bfloat16(u.z); o.h[3] = __float2bfloat16(u.w);
  o.h[4] = __float2bfloat16(v.x); o.h[5] = __float2bfloat16(v.y);
  o.h[6] = __float2bfloat16(v.z); o.h[7] = __float2bfloat16(v.w);
  return o.r;
}

// Wave-parallel (64 lanes): lane l watches slot l until ALL slots >= tgt.
__device__ __forceinline__ void wave_poll(const unsigned* base, int lane,
                                          unsigned tgt) {
  const unsigned* p = base + lane * FSTRIDE;
  for (;;) {
    unsigned v = __hip_atomic_load(p, __ATOMIC_RELAXED,
                                   __HIP_MEMORY_SCOPE_AGENT);
    if (__all((int)(v >= tgt))) break;
    __builtin_amdgcn_s_sleep(1);
  }
}

// Single-lane poll of one word.
__device__ __forceinline__ void poll_ge(const unsigned* p, unsigned tgt) {
  while (__hip_atomic_load(p, __ATOMIC_RELAXED,
                           __HIP_MEMORY_SCOPE_AGENT) < tgt)
    __builtin_amdgcn_s_sleep(1);
}

// Ring-slice GEMM half: K=512 as 16 kk steps. A rows {arow, arow+16} from
// device-coherent ring memory via raw asm global_load_dwordx4 sc0 sc1
// (L1/L2-bypass, but plain VMEM: compiler cannot serialize it). Two batches
// of 16 loads; all 32 in flight before the first wait. Immediate offsets
// (u*64B <= 960) keep address regs at two pairs.
template<int WBASE>
__device__ __forceinline__ void ring_gemm(const bf16* abase,      // + arow*H
                                          const bf16* Wl, int nb, int sw,
                                          int quad, f32x4& acc0, f32x4& acc1) {
  const bf16* base0 = abase + quad * 8;                  // row arow
  const bf16* base1 = base0 + (size_t)16 * H;            // row arow+16
  bf16x8 A0[8], A1[8], B0[8], B1[8];
  #pragma unroll
  for (int u = 0; u < 8; ++u) {                          // batch 0: kk 0..7
    asm volatile("global_load_dwordx4 %0, %1, off offset:%c2 sc0 sc1"
                 : "=v"(A0[u]) : "v"(base0), "i"(u * 64));
    asm volatile("global_load_dwordx4 %0, %1, off offset:%c2 sc0 sc1"
                 : "=v"(A1[u]) : "v"(base1), "i"(u * 64));
  }
  #pragma unroll
  for (int u = 0; u < 8; ++u) {                          // batch 1: kk 8..15
    asm volatile("global_load_dwordx4 %0, %1, off offset:%c2 sc0 sc1"
                 : "=v"(B0[u]) : "v"(base0), "i"(512 + u * 64));
    asm volatile("global_load_dwordx4 %0, %1, off offset:%c2 sc0 sc1"
                 : "=v"(B1[u]) : "v"(base1), "i"(512 + u * 64));
  }
  asm volatile("s_waitcnt vmcnt(16)" ::: "memory");      // batch 0 landed
  __builtin_amdgcn_sched_barrier(0);
  #pragma unroll
  for (int u = 0; u < 8; ++u) {
    const int wblk = WBASE + u * 4 + quad;
    bf16x8 bfr = *(const bf16x8*)(Wl + nb * 1024 + ((wblk ^ sw) * 8));
    acc0 = __builtin_amdgcn_mfma_f32_16x16x32_bf16(A0[u], bfr, acc0, 0, 0, 0);
    acc1 = __builtin_amdgcn_mfma_f32_16x16x32_bf16(A1[u], bfr, acc1, 0, 0, 0);
  }
  asm volatile("s_waitcnt vmcnt(0)" ::: "memory");       // batch 1 landed
  __builtin_amdgcn_sched_barrier(0);
  #pragma unroll
  for (int u = 0; u < 8; ++u) {
    const int wblk = WBASE + (8 + u) * 4 + quad;
    bf16x8 bfr = *(const bf16x8*)(Wl + nb * 1024 + ((wblk ^ sw) * 8));
    acc0 = __builtin_amdgcn_mfma_f32_16x16x32_bf16(B0[u], bfr, acc0, 0, 0, 0);
    acc1 = __builtin_amdgcn_mfma_f32_16x16x32_bf16(B1[u], bfr, acc1, 0, 0, 0);
  }
}

__global__ void __launch_bounds__(256, 1)
lstm_bidir(const float* __restrict__ x,
           const float* Wxf, const float* bxf, const float* Whf, const float* bhf,
           const float* Wxb, const float* bxb, const float* Whb, const float* bhb,
           float* out)
{
  __shared__ bf16 Wl[32 * 1024];   // 64 KB: 32 gate-col rows x K=1024 (swizzled)
  __shared__ float sh[64][8];      // 2 KB: per-round h tile (f32), for coalesce

  const int tid   = threadIdx.x;
  const int bid   = blockIdx.x;
  const int stage = bid & 3;       // L0F,L0B,L1F,L1B
  const int wg    = bid >> 2;      // 0..63
  const int dir   = stage & 1;
  const int layer = stage >> 1;
  const int c0    = wg * 8;        // h-col base owned by this WG

  const float* Wx = dir ? Wxb : Wxf;
  const float* Wh = dir ? Whb : Whf;
  const float* bx = dir ? bxb : bxf;
  const float* bh = dir ? bhb : bhf;
  bf16* ring  = g_ring  + (size_t)dir * W * B * H;  // L0 h (also L1's x source)
  bf16* ring2 = g_ring2 + (size_t)dir * W * B * H;  // L1 h recurrence

  // ---- stage weight slice into LDS (fp32 -> bf16); row n = j*4+g
  // 16B block kb stored at physical block kb ^ (n&7)  (bank de-conflict)
  for (int c = tid; c < 32 * 128; c += 256) {
    const int n  = c >> 7;               // 0..31
    const int kb = c & 127;              // 16B-bf16 block in K
    const int ke = kb * 8;               // elem offset 0..1016
    const int j = n >> 2, g = n & 3;
    const size_t row = (size_t)layer * G4 + (size_t)g * H + (c0 + j);
    const float* src = (ke < H) ? (Wx + row * H + ke) : (Wh + row * H + (ke - H));
    bf16x8 wv = cvt8(src);
    *(bf16x8*)(Wl + n * 1024 + ((kb ^ (n & 7)) * 8)) = wv;
  }

  const int lane = tid & 63, wi = tid >> 6;   // 4 waves
  const int quad = lane >> 4, mr = lane & 15;
  const int g2 = wi & 1;          // wave's 16-col group
  const int mh = wi >> 1;         // wave's 32-row half
  const int nb = g2 * 16 + mr;    // gate col within WG (0..31)
  const int j  = nb >> 2, gg = nb & 3;        // h-col within WG, gate id
  const int sw = nb & 7;          // swizzle key for this lane's B row

  const size_t brow = (size_t)layer * G4 + (size_t)gg * H + (c0 + j);
  const float bias = bx[brow] + bh[brow];     // fp32

  __syncthreads();  // weights ready (intra-WG)

  float cst[2][4] = {};           // c-state rows mh*32+m*16+quad*4+rr, col j
  unsigned nrounds = 0;           // rounds completed by this WG
  unsigned*       myflags   = g_flags + stage * NW * FSTRIDE;
  unsigned*       myepoch   = g_epoch + stage * ESTRIDE;
  const unsigned* prodepoch = g_epoch + dir * ESTRIDE;        // L1 <- L0
  const unsigned* consepoch = g_epoch + (2 + dir) * ESTRIDE;  // L0 <- L1

  const int r0 = (stage < 2) ? 0 : 1;
  for (int r = r0; r < r0 + T; ++r) {
    int t;
    if (stage == 0)      t = r;
    else if (stage == 1) t = (T - 1) - r;
    else if (stage == 2) t = r - 1;
    else                 t = T - r;

    const bool first = dir ? (t == T - 1) : (t == 0);
    const bool last  = dir ? (t == 0) : (t == T - 1);

    const float* xf = nullptr;      // L0: fp32 x
    const bf16 *xsb = nullptr;      // L1: bf16 x (= L0 ring)
    const bf16 *hsrc; bf16* hdst_bf; float* hdst_f32 = nullptr;
    if (stage < 2) {
      xf      = x    + (size_t)t * B * H;
      hsrc    = ring + (size_t)((r - 1) & (W - 1)) * B * H;
      hdst_bf = ring + (size_t)(r & (W - 1)) * B * H;
    } else {
      xsb      = ring  + (size_t)((r - 1) & (W - 1)) * B * H;  // L0's h for step t
      hsrc     = ring2 + (size_t)((r - 1) & (W - 1)) * B * H;  // own h_{t-1}
      hdst_bf  = ring2 + (size_t)(r & (W - 1)) * B * H;
      hdst_f32 = out + (size_t)t * B * 1024 + (size_t)dir * H;
    }

    // ---- GEMM: C[64,32] = [x_t ; h_{t-1}] (K=1024) @ Wslice, fp32 accum
    f32x4 acc0 = {0.f, 0.f, 0.f, 0.f};
    f32x4 acc1 = {0.f, 0.f, 0.f, 0.f};
    const int arow = mh * 32 + mr;

    if (stage < 2) {
      #pragma unroll
      for (int kk = 0; kk < 16; ++kk) {   // x part (fp32 -> bf16): K 0..511
        const int blk = kk * 4 + quad;
        bf16x8 bfr = *(const bf16x8*)(Wl + nb * 1024 + ((blk ^ sw) * 8));
        const float* ap = xf + (size_t)arow * H + blk * 8;
        bf16x8 a0 = cvt8(ap);
        bf16x8 a1 = cvt8(ap + (size_t)16 * H);
        acc0 = __builtin_amdgcn_mfma_f32_16x16x32_bf16(a0, bfr, acc0, 0, 0, 0);
        acc1 = __builtin_amdgcn_mfma_f32_16x16x32_bf16(a1, bfr, acc1, 0, 0, 0);
      }
      // ---- waits, hidden behind the x-part GEMM above:
      //  siblings done round r-1 (gates h-part reads) + L1 back-pressure
      //  (gates this round's ring writes).
      if (tid < 64) {
        if (wg == 0) {
          wave_poll(myflags, tid, nrounds);       // scan 64 flags (aggregator)
          if (tid == 0) {
            __hip_atomic_store(myepoch, nrounds, __ATOMIC_RELAXED,
                               __HIP_MEMORY_SCOPE_AGENT);
            if (r >= W) poll_ge(consepoch, (unsigned)(r - W + 1));
          }
        } else if (tid == 0) {
          poll_ge(myepoch, nrounds);              // single-word sibling wait
          if (r >= W) poll_ge(consepoch, (unsigned)(r - W + 1));
        }
      }
      __syncthreads();
      if (!first)
        ring_gemm<64>(hsrc + (size_t)arow * H, Wl, nb, sw, quad, acc0, acc1);
    } else {
      // producer wait: every L0 WG published round r. Steady state: L0 runs
      // up to ~W ahead -> this poll is a single satisfied fabric load.
      if (tid == 0) poll_ge(prodepoch, (unsigned)r);
      __syncthreads();
      ring_gemm<0>(xsb + (size_t)arow * H, Wl, nb, sw, quad, acc0, acc1);
      // sibling wait (gates h-part), hidden behind the x-part GEMM above.
      if (tid < 64) {
        if (wg == 0) {
          wave_poll(myflags, tid, nrounds);
          if (tid == 0)
            __hip_atomic_store(myepoch, nrounds, __ATOMIC_RELAXED,
                               __HIP_MEMORY_SCOPE_AGENT);
        } else if (tid == 0) {
          poll_ge(myepoch, nrounds);
        }
      }
      __syncthreads();
      if (!first)
        ring_gemm<64>(hsrc + (size_t)arow * H, Wl, nb, sw, quad, acc0, acc1);
    }

    // ---- gates: lane holds gate gg of (row, col j); partners in lanes ^1^2^3
    #pragma unroll
    for (int m = 0; m < 2; ++m) {
      const f32x4 av = m ? acc1 : acc0;
      #pragma unroll
      for (int rr = 0; rr < 4; ++rr) {
        const float v  = av[rr] + bias;
        const float v1 = __shfl_xor(v, 1);
        const float v2 = __shfl_xor(v, 2);
        const float v3 = __shfl_xor(v, 3);
        float gi, gf, gc, go;
        if (gg == 0)      { gi = v;  gf = v1; gc = v2; go = v3; }
        else if (gg == 1) { gi = v1; gf = v;  gc = v3; go = v2; }
        else if (gg == 2) { gi = v2; gf = v3; gc = v;  go = v1; }
        else              { gi = v3; gf = v2; gc = v1; go = v;  }
        const float si = 1.f / (1.f + __expf(-gi));
        const float sf = 1.f / (1.f + __expf(-gf));
        const float so = 1.f / (1.f + __expf(-go));
        const float tc = 1.f - 2.f / (1.f + __expf(2.f * gc));   // tanh, sat-safe
        const float c2 = sf * cst[m][rr] + si * tc;
        cst[m][rr] = c2;
        const float th = 1.f - 2.f / (1.f + __expf(2.f * c2));
        const float hv = so * th;
        if (gg == 0) {
          const int b = mh * 32 + m * 16 + quad * 4 + rr;
          sh[b][j] = hv;                         // stage for coalesced publish
          if (last) {
            const size_t p = (size_t)(dir * 2 + layer) * (B * H) + (size_t)b * H + (c0 + j);
            out[HID_OFF + p]  = hv;
            out[CELL_OFF + p] = c2;
          }
        }
      }
    }

    // ---- coalesced publish: wave 0 re-reads the 64x8 f32 tile and emits
    // 2 coherent 8B ring stores per row (+ float4 out stores for L1), then
    // drains and the flag goes up. Other waves pass the final barrier and
    // start the next round's x-part immediately.
    __syncthreads();    // sh complete
    if (tid < 64) {
      const int b = tid;
      const float4 u0 = *(const float4*)&sh[b][0];
      const float4 u1 = *(const float4*)&sh[b][4];
      union { bf16 h[8]; u64 q[2]; } o;
      o.h[0] = __float2bfloat16(u0.x); o.h[1] = __float2bfloat16(u0.y);
      o.h[2] = __float2bfloat16(u0.z); o.h[3] = __float2bfloat16(u0.w);
      o.h[4] = __float2bfloat16(u1.x); o.h[5] = __float2bfloat16(u1.y);
      o.h[6] = __float2bfloat16(u1.z); o.h[7] = __float2bfloat16(u1.w);
      bf16* rp = hdst_bf + (size_t)b * H + c0;
      __hip_atomic_store((u64*)rp,     o.q[0], __ATOMIC_RELAXED,
                         __HIP_MEMORY_SCOPE_AGENT);
      __hip_atomic_store((u64*)rp + 1, o.q[1], __ATOMIC_RELAXED,
                         __HIP_MEMORY_SCOPE_AGENT);
      if (stage >= 2) {
        float* op = hdst_f32 + (size_t)b * 1024 + c0;
        *(float4*)op       = u0;
        *(float4*)(op + 4) = u1;
      }
      asm volatile("s_waitcnt vmcnt(0)" ::: "memory");  // ring stores visible
    }
    __syncthreads();    // wave 0 done with sh + stores drained
    ++nrounds;
    if (tid == 0) {
      __hip_atomic_store(myflags + wg * FSTRIDE, nrounds,
                         __ATOMIC_RELAXED, __HIP_MEMORY_SCOPE_AGENT);
    }
  }

  // final epoch publish (consumers' last-round targets reference epoch == T)
  if (wg == 0 && tid < 64) {
    wave_poll(myflags, tid, (unsigned)T);
    if (tid == 0)
      __hip_atomic_store(myepoch, (unsigned)T, __ATOMIC_RELAXED,
                         __HIP_MEMORY_SCOPE_AGENT);
  }
}

extern "C" void kernel_launch(void* const* d_in, const int* in_sizes, int n_in,
                              void* d_out, int out_size, void* d_ws, size_t ws_size,
                              hipStream_t stream) {
  const float* x   = (const float*)d_in[0];
  const float* Wxf = (const float*)d_in[1];
  const float* bxf = (const float*)d_in[2];
  const float* Whf = (const float*)d_in[3];
  const float* bhf = (const float*)d_in[4];
  const float* Wxb = (const float*)d_in[5];
  const float* bxb = (const float*)d_in[6];
  const float* Whb = (const float*)d_in[7];
  const float* bhb = (const float*)d_in[8];
  float* out = (float*)d_out;

  hipLaunchKernelGGL(init_ctrs, dim3(16), dim3(256), 0, stream);
  hipLaunchKernelGGL(lstm_bidir, dim3(256), dim3(256), 0, stream,
                     x, Wxf, bxf, Whf, bhf, Wxb, bxb, Whb, bhb, out);
}